// Round 4
// baseline (218.913 us; speedup 1.0000x reference)
//
#include <hip/hip_runtime.h>

#define B_    8
#define V_    50000
#define KNB   9
#define CIN_  64
#define COUT_ 128
#define VOUT_ 12500
#define NNZ_  37500
#define KTOT  576      // KNB*CIN_
#define M_    400000   // B_*V_

typedef short bf16x8 __attribute__((ext_vector_type(8)));
typedef float f32x4  __attribute__((ext_vector_type(4)));

#define AS1 __attribute__((address_space(1)))
#define AS3 __attribute__((address_space(3)))

__device__ __forceinline__ unsigned short f2bf(float f) {
  unsigned u = __float_as_uint(f);
  u += 0x7fffu + ((u >> 16) & 1u);          // RNE
  return (unsigned short)(u >> 16);
}
__device__ __forceinline__ float bf2f(unsigned short u) {
  return __uint_as_float((unsigned)u << 16);
}

__device__ __forceinline__ void gld_lds16(const void* g, void* l) {
  __builtin_amdgcn_global_load_lds((const AS1 unsigned*)g, (AS3 unsigned*)l, 16, 0, 0);
}

__global__ __launch_bounds__(256) void convert_w(const float* __restrict__ w,
                                                 unsigned short* __restrict__ wbf) {
  int i = blockIdx.x * 256 + threadIdx.x;   // grid sized exactly to COUT_*KTOT
  wbf[i] = f2bf(w[i]);
}

__global__ __launch_bounds__(256) void convert_x(const float* __restrict__ x,
                                                 unsigned short* __restrict__ xbf) {
  const int nq = B_ * V_ * CIN_ / 4;        // 6.4M float4 quads
  for (int q = blockIdx.x * 256 + threadIdx.x; q < nq; q += 2048 * 256) {
    float4 f = reinterpret_cast<const float4*>(x)[q];
    ushort4 o;
    o.x = f2bf(f.x); o.y = f2bf(f.y); o.z = f2bf(f.z); o.w = f2bf(f.w);
    reinterpret_cast<ushort4*>(xbf)[q] = o;
  }
}

// h[m][c] = elu( sum_k A[m][k]*W[c][k] + bias[c] ), A gathered (bf16) via spiral_indices.
// 128x128 tile, 4 waves, BK=64. Counted-vmcnt pipeline (T3/T4-lite):
//   A: 3 LDS buffers, staged 2 K-steps ahead (covers ~900cyc HBM gather latency)
//   B: 2 LDS buffers, staged 1 K-step ahead (covers L2 latency; W is L2-resident)
//   one raw s_barrier per K-step; steady-state wait = vmcnt(4), NEVER 0 until the tail.
// VMEM issue order per iter t (after barrier): B(t+1)[4], A(t+2)[4].
// Entry of iter t: outstanding = A(t)[4], B(t)[4], A(t+1)[4] -> vmcnt(4) drains A(t),B(t).
__global__ __launch_bounds__(256, 2) void spiral_gemm(
    const unsigned short* __restrict__ xbf, const unsigned short* __restrict__ wbf,
    const float* __restrict__ bias, const int* __restrict__ sp,
    unsigned short* __restrict__ hbf)
{
  __shared__ char smem[81920];         // A: 3 x 16KB @0, B: 2 x 16KB @49152
  char* const Abase = smem;
  char* const Bbase = smem + 49152;

  const int tid  = threadIdx.x;
  const int m0   = blockIdx.x * 128;
  const int wave = tid >> 6;

  // ---- staging geometry: 4 rounds x 32 rows, 8 chunks of 16B per 128B row
  const int rrow  = tid >> 3;                       // 0..31
  const int chunk = tid & 7;
  const int chunkoff = ((chunk ^ (rrow & 7)) << 4); // inverse-swizzled source chunk

  const unsigned short* xbase[4];
  const char* wcb[4];
  int ldsoff[4];
  int idxs[4][KNB];                                  // all spiral indices up-front (regs)
  #pragma unroll
  for (int r = 0; r < 4; ++r) {
    int row = r * 32 + rrow;
    int m = m0 + row;
    int b = m / V_;
    int v = m - b * V_;
    xbase[r] = xbf + (size_t)b * (V_ * CIN_);
    const int* spr = sp + v * KNB;
    #pragma unroll
    for (int t = 0; t < KNB; ++t) idxs[r][t] = spr[t];
    wcb[r] = (const char*)wbf + (size_t)row * (KTOT * 2) + chunkoff;
    ldsoff[r] = (r * 32 + wave * 8) * 128;           // wave-uniform LDS base per round
  }

  // ---- compute geometry
  const int wr = wave >> 1, wc = wave & 1;
  const int lane = tid & 63;
  const int lr = lane & 15, lg = lane >> 4;
  int aoff[4], aswz[4], boff[4], bswz[4];
  #pragma unroll
  for (int m = 0; m < 4; ++m) {
    int row = wr * 64 + m * 16 + lr;
    aoff[m] = row * 128; aswz[m] = (row & 7) << 4;
    int col = wc * 64 + m * 16 + lr;
    boff[m] = col * 128; bswz[m] = (col & 7) << 4;
  }

  f32x4 acc[4][4];
  #pragma unroll
  for (int i = 0; i < 4; ++i)
    #pragma unroll
    for (int j = 0; j < 4; ++j)
      acc[i][j] = (f32x4){0.f, 0.f, 0.f, 0.f};

  auto stageA = [&](char* Ab, int t) {
    #pragma unroll
    for (int r = 0; r < 4; ++r)
      gld_lds16((const char*)xbase[r] + (size_t)idxs[r][t] * 128 + chunkoff, Ab + ldsoff[r]);
  };
  auto stageB = [&](char* Bb, int t) {
    #pragma unroll
    for (int r = 0; r < 4; ++r)
      gld_lds16(wcb[r] + t * 128, Bb + ldsoff[r]);
  };
  auto compute = [&](const char* Ab, const char* Bb) {
    #pragma unroll
    for (int ks = 0; ks < 2; ++ks) {
      const int kb = ks * 64 + lg * 16;
      bf16x8 af[4], bfr[4];
      #pragma unroll
      for (int m = 0; m < 4; ++m)
        af[m] = *reinterpret_cast<const bf16x8*>(Ab + aoff[m] + (kb ^ aswz[m]));
      #pragma unroll
      for (int n = 0; n < 4; ++n)
        bfr[n] = *reinterpret_cast<const bf16x8*>(Bb + boff[n] + (kb ^ bswz[n]));
      __builtin_amdgcn_s_setprio(1);
      #pragma unroll
      for (int m = 0; m < 4; ++m)
        #pragma unroll
        for (int n = 0; n < 4; ++n)
          acc[m][n] = __builtin_amdgcn_mfma_f32_16x16x32_bf16(af[m], bfr[n], acc[m][n], 0, 0, 0);
      __builtin_amdgcn_s_setprio(0);
    }
  };

  // ---- prologue: A(0), B(0), A(1)  (order matters for the vmcnt arithmetic)
  stageA(Abase, 0);
  stageB(Bbase, 0);
  stageA(Abase + 16384, 1);

  // ---- main loop, fully unrolled so buffer indices & wait immediates are constants
  #pragma unroll
  for (int t = 0; t < KNB; ++t) {
    if (t < KNB - 1) { asm volatile("s_waitcnt vmcnt(4)" ::: "memory"); }
    else             { asm volatile("s_waitcnt vmcnt(0)" ::: "memory"); }
    __builtin_amdgcn_s_barrier();
    __builtin_amdgcn_sched_barrier(0);
    if (t + 1 < KNB) stageB(Bbase + 16384 * ((t + 1) & 1), t + 1);
    if (t + 2 < KNB) stageA(Abase + 16384 * ((t + 2) % 3), t + 2);
    compute(Abase + 16384 * (t % 3), Bbase + 16384 * (t & 1));
    __builtin_amdgcn_sched_barrier(0);
  }
  __syncthreads();   // full drain before reusing smem for the epilogue

  // ---- epilogue: bias + ELU -> bf16, re-layout via LDS for coalesced 16B stores
  unsigned short* hs = (unsigned short*)smem;   // [128][136] (pad: 272B row, 16-aligned)
  #pragma unroll
  for (int n = 0; n < 4; ++n) {
    const int c = wc * 64 + n * 16 + lr;
    const float bv = bias[c];
    #pragma unroll
    for (int m = 0; m < 4; ++m) {
      const int row = wr * 64 + m * 16 + lg * 4;
      #pragma unroll
      for (int j = 0; j < 4; ++j) {
        float vv = acc[m][n][j] + bv;
        vv = vv > 0.f ? vv : (__expf(vv) - 1.f);
        hs[(row + j) * 136 + c] = f2bf(vv);
      }
    }
  }
  __syncthreads();
  const int r2 = tid >> 1, hf = tid & 1;
  const uint4* srow = reinterpret_cast<const uint4*>((const char*)hs + r2 * 272 + hf * 128);
  uint4* drow = reinterpret_cast<uint4*>(hbf + (size_t)(m0 + r2) * COUT_ + hf * 64);
  #pragma unroll
  for (int u = 0; u < 8; ++u) drow[u] = srow[u];
}

// ---------------- pool: CSR build (count / scan / fill), then row-major gather ----------

__global__ __launch_bounds__(256) void pool_count(const int* __restrict__ dr,
                                                  int* __restrict__ counts) {
  int e = blockIdx.x * 256 + threadIdx.x;
  if (e < NNZ_) atomicAdd(&counts[dr[e]], 1);
}

// 12500 elems: 256 threads x 49-chunk serial scan + 8-step block scan (8 barrier pairs).
__global__ __launch_bounds__(256) void pool_scan(const int* __restrict__ counts,
                                                 int* __restrict__ offsets,
                                                 int* __restrict__ cursor) {
  __shared__ int part[256];
  const int t = threadIdx.x;
  const int c0 = t * 49;
  int s = 0;
  for (int i = 0; i < 49; ++i) {
    int j = c0 + i;
    if (j < VOUT_) s += counts[j];
  }
  part[t] = s;
  __syncthreads();
  #pragma unroll
  for (int off = 1; off < 256; off <<= 1) {
    int v = (t >= off) ? part[t - off] : 0;
    __syncthreads();
    part[t] += v;
    __syncthreads();
  }
  int run = part[t] - s;                 // exclusive prefix of my chunk
  for (int i = 0; i < 49; ++i) {
    int j = c0 + i;
    if (j < VOUT_) {
      offsets[j] = run; cursor[j] = run;
      run += counts[j];
    }
  }
  if (t == 255) offsets[VOUT_] = part[255];   // == NNZ_
}

__global__ __launch_bounds__(256) void pool_fill(const int* __restrict__ dr,
                                                 const int* __restrict__ dc,
                                                 const float* __restrict__ dd,
                                                 int* __restrict__ cursor,
                                                 int2* __restrict__ elist) {
  int e = blockIdx.x * 256 + threadIdx.x;
  if (e < NNZ_) {
    int slot = atomicAdd(&cursor[dr[e]], 1);
    elist[slot] = make_int2(dc[e], __float_as_int(dd[e]));
  }
}

// One block per output row; 8 b-groups x 32 lanes; each lane owns 4 c's (ushort4/float4).
// Fully overwrites out -> no memset of d_out needed.
__global__ __launch_bounds__(256) void pool_rows(const unsigned short* __restrict__ hbf,
                                                 const int* __restrict__ offsets,
                                                 const int2* __restrict__ elist,
                                                 float* __restrict__ out) {
  const int row = blockIdx.x;
  const int bg = threadIdx.x >> 5;     // batch 0..7
  const int lc = threadIdx.x & 31;     // c-quad 0..31
  const int s = offsets[row], e1 = offsets[row + 1];
  const unsigned short* hb = hbf + (size_t)bg * (V_ * COUT_) + lc * 4;
  float4 acc = {0.f, 0.f, 0.f, 0.f};
  for (int e = s; e < e1; ++e) {
    int2 en = elist[e];
    float d = __int_as_float(en.y);
    ushort4 v = *reinterpret_cast<const ushort4*>(hb + (size_t)en.x * COUT_);
    acc.x += d * bf2f(v.x);
    acc.y += d * bf2f(v.y);
    acc.z += d * bf2f(v.z);
    acc.w += d * bf2f(v.w);
  }
  *reinterpret_cast<float4*>(out + ((size_t)bg * VOUT_ + row) * COUT_ + lc * 4) = acc;
}

extern "C" void kernel_launch(void* const* d_in, const int* in_sizes, int n_in,
                              void* d_out, int out_size, void* d_ws, size_t ws_size,
                              hipStream_t stream) {
  const float* x    = (const float*)d_in[0];
  const float* w    = (const float*)d_in[1];
  const float* bias = (const float*)d_in[2];
  const int*   sp   = (const int*)d_in[3];
  const int*   dr   = (const int*)d_in[4];
  const int*   dc   = (const int*)d_in[5];
  const float* dd   = (const float*)d_in[6];
  float* out = (float*)d_out;

  char* ws = (char*)d_ws;
  unsigned short* wbf = (unsigned short*)ws;                       // 147,456 B
  unsigned short* xbf = (unsigned short*)(ws + 147456);            // 51,200,000 B
  unsigned short* hbf = (unsigned short*)(ws + 51347456);          // 102,400,000 B
  int*  counts  = (int*) (ws + 153747456);                         // 50,000 B
  int*  cursor  = (int*) (ws + 153797456);                         // 50,000 B
  int*  offsets = (int*) (ws + 153847456);                         // 50,004 B
  int2* elist   = (int2*)(ws + 153897464);                         // 300,000 B

  convert_w<<<288, 256, 0, stream>>>(w, wbf);
  convert_x<<<2048, 256, 0, stream>>>(x, xbf);
  hipMemsetAsync(counts, 0, VOUT_ * sizeof(int), stream);
  pool_count<<<(NNZ_ + 255) / 256, 256, 0, stream>>>(dr, counts);
  pool_scan<<<1, 256, 0, stream>>>(counts, offsets, cursor);
  pool_fill<<<(NNZ_ + 255) / 256, 256, 0, stream>>>(dr, dc, dd, cursor, elist);
  spiral_gemm<<<M_ / 128, 256, 0, stream>>>(xbf, wbf, bias, sp, hbf);
  pool_rows<<<VOUT_, 256, 0, stream>>>(hbf, offsets, elist, out);
}

// Round 5
// 210.536 us; speedup vs baseline: 1.0398x; 1.0398x over previous
//
#include <hip/hip_runtime.h>

#define B_    8
#define V_    50000
#define KNB   9
#define CIN_  64
#define COUT_ 128
#define VOUT_ 12500
#define NNZ_  37500
#define KTOT  576      // KNB*CIN_
#define M_    400000   // B_*V_

typedef short bf16x8 __attribute__((ext_vector_type(8)));
typedef float f32x4  __attribute__((ext_vector_type(4)));

#define AS1 __attribute__((address_space(1)))
#define AS3 __attribute__((address_space(3)))

__device__ __forceinline__ unsigned short f2bf(float f) {
  unsigned u = __float_as_uint(f);
  u += 0x7fffu + ((u >> 16) & 1u);          // RNE
  return (unsigned short)(u >> 16);
}
__device__ __forceinline__ float bf2f(unsigned short u) {
  return __uint_as_float((unsigned)u << 16);
}

__device__ __forceinline__ void gld_lds16(const void* g, void* l) {
  __builtin_amdgcn_global_load_lds((const AS1 unsigned*)g, (AS3 unsigned*)l, 16, 0, 0);
}

// Weight -> MFMA-fragment-major bf16: chunk i (16B) holds, for
// lane=i&63, n=(i>>6)&3, wc=(i>>8)&1, ks=(i>>9)&1, t=i>>10:
//   W[col = wc*64+n*16+(lane&15)][k = t*64+ks*32+(lane>>4)*8 .. +8]
// so a wave's B-fragment load is one coalesced dwordx4 per (t,ks,n).
__global__ __launch_bounds__(256) void convert_w_frag(const float* __restrict__ w,
                                                      unsigned short* __restrict__ wfr) {
  int i = blockIdx.x * 256 + threadIdx.x;        // 0..9215 (grid sized exactly)
  int lane = i & 63, n = (i >> 6) & 3, wc = (i >> 8) & 1, ks = (i >> 9) & 1, t = i >> 10;
  int col = wc * 64 + n * 16 + (lane & 15);
  int k0 = t * 64 + ks * 32 + (lane >> 4) * 8;
  const float* src = w + (size_t)col * KTOT + k0;
  float4 f0 = reinterpret_cast<const float4*>(src)[0];
  float4 f1 = reinterpret_cast<const float4*>(src)[1];
  uint4 o;
  o.x = (unsigned)f2bf(f0.x) | ((unsigned)f2bf(f0.y) << 16);
  o.y = (unsigned)f2bf(f0.z) | ((unsigned)f2bf(f0.w) << 16);
  o.z = (unsigned)f2bf(f1.x) | ((unsigned)f2bf(f1.y) << 16);
  o.w = (unsigned)f2bf(f1.z) | ((unsigned)f2bf(f1.w) << 16);
  reinterpret_cast<uint4*>(wfr)[i] = o;
}

__global__ __launch_bounds__(256) void convert_x(const float* __restrict__ x,
                                                 unsigned short* __restrict__ xbf) {
  const int nq = B_ * V_ * CIN_ / 4;        // 6.4M float4 quads
  for (int q = blockIdx.x * 256 + threadIdx.x; q < nq; q += 2048 * 256) {
    float4 f = reinterpret_cast<const float4*>(x)[q];
    ushort4 o;
    o.x = f2bf(f.x); o.y = f2bf(f.y); o.z = f2bf(f.z); o.w = f2bf(f.w);
    reinterpret_cast<ushort4*>(xbf)[q] = o;
  }
}

// h = elu(gather(x) @ W^T + bias). 128x128 tile, 4 waves (2x2 of 64x64), BK=64.
// A: gathered rows staged via global_load_lds into 3 LDS buffers (2-deep prefetch,
//    pre-swizzled global source, swizzled ds_read).  B: NO LDS — fragment-major
//    global loads into registers each K-step (W is L1/L2-resident, 147KB).
// LDS = 48KB -> 3 blocks/CU (12 waves); VGPR target <=170 for 3 waves/SIMD.
// VMEM queue per iter t: [B(t) x8 dwordx4][A(t+2) x4 gld_lds].
// Entry-of-t guarantee needed: A(t) LDS-writes complete. Worst-case queue at entry:
//   A(t)[4] (iter t-2), B(t-1)[8]+A(t+1)[4] (iter t-1)  -> A(t) is >=8 deep
//   => s_waitcnt vmcnt(4) always suffices (leaves at most A(t+1) in flight).
// Compiler inserts its own waits for breg register deps (it models gld_lds in vmcnt).
__global__ __launch_bounds__(256, 3) void spiral_gemm(
    const unsigned short* __restrict__ xbf, const unsigned short* __restrict__ wfr,
    const float* __restrict__ bias, const int* __restrict__ sp,
    unsigned short* __restrict__ hbf)
{
  __shared__ char Abuf[49152];     // 3 x 16KB (epilogue reuses as hs)

  const int tid  = threadIdx.x;
  const int m0   = blockIdx.x * 128;
  const int wave = tid >> 6;
  const int lane = tid & 63;

  // ---- staging geometry: 4 rounds x 32 rows, 8 lanes x 16B chunks per 128B row
  const int rrow  = tid >> 3;                       // 0..31
  const int chunk = tid & 7;
  const int chunkoff = ((chunk ^ (rrow & 7)) << 4); // inverse-swizzled source chunk

  unsigned boff[4];
  int idxs[4][KNB];
  #pragma unroll
  for (int r = 0; r < 4; ++r) {
    int row = r * 32 + rrow;
    int m = m0 + row;
    int b = m / V_;
    int v = m - b * V_;
    boff[r] = (unsigned)b * (V_ * CIN_ * 2);        // byte offset of batch slice
    const int* spr = sp + v * KNB;
    #pragma unroll
    for (int t = 0; t < KNB; ++t) idxs[r][t] = spr[t];
  }

  // ---- compute geometry
  const int wr = wave >> 1, wc = wave & 1;
  const int lr = lane & 15, lg = lane >> 4;
  const bf16x8* wbase = (const bf16x8*)wfr + wc * 256 + lane;   // +((t*2+ks)*512 + n*64)

  f32x4 acc[4][4];
  #pragma unroll
  for (int i = 0; i < 4; ++i)
    #pragma unroll
    for (int j = 0; j < 4; ++j)
      acc[i][j] = (f32x4){0.f, 0.f, 0.f, 0.f};

  auto stageA = [&](char* Ab, int t) {
    #pragma unroll
    for (int r = 0; r < 4; ++r) {
      unsigned off = boff[r] + (unsigned)idxs[r][t] * 128u + (unsigned)chunkoff;
      gld_lds16((const char*)xbf + off, Ab + (r * 32 + wave * 8) * 128);
    }
  };

  // ---- prologue: A(0), A(1)
  stageA(Abuf, 0);
  stageA(Abuf + 16384, 1);

  // ---- main loop (fully unrolled; buffer sel & wait immediates constant)
  #pragma unroll
  for (int t = 0; t < KNB; ++t) {
    asm volatile("s_waitcnt vmcnt(4)" ::: "memory");
    __builtin_amdgcn_s_barrier();
    __builtin_amdgcn_sched_barrier(0);

    // B(t) fragments -> registers (8 x dwordx4, L1/L2-resident)
    bf16x8 breg[2][4];
    #pragma unroll
    for (int ks = 0; ks < 2; ++ks)
      #pragma unroll
      for (int n = 0; n < 4; ++n)
        breg[ks][n] = wbase[(t * 2 + ks) * 512 + n * 64];

    // A(t+2) stage (2-deep)
    if (t + 2 < KNB) stageA(Abuf + 16384 * ((t + 2) % 3), t + 2);
    __builtin_amdgcn_sched_barrier(0);

    // compute from A-buffer t%3
    const char* Ab = Abuf + 16384 * (t % 3);
    #pragma unroll
    for (int ks = 0; ks < 2; ++ks) {
      const int kb = ks * 64 + lg * 16;
      bf16x8 af[4];
      #pragma unroll
      for (int m = 0; m < 4; ++m) {
        int row = wr * 64 + m * 16 + lr;
        af[m] = *reinterpret_cast<const bf16x8*>(Ab + row * 128 + (kb ^ ((row & 7) << 4)));
      }
      __builtin_amdgcn_s_setprio(1);
      #pragma unroll
      for (int m = 0; m < 4; ++m)
        #pragma unroll
        for (int n = 0; n < 4; ++n)
          acc[m][n] = __builtin_amdgcn_mfma_f32_16x16x32_bf16(af[m], breg[ks][n], acc[m][n], 0, 0, 0);
      __builtin_amdgcn_s_setprio(0);
    }
  }
  __syncthreads();   // full drain before reusing Abuf for the epilogue

  // ---- epilogue: bias + ELU -> bf16, re-layout via LDS for coalesced 16B stores
  unsigned short* hs = (unsigned short*)Abuf;   // [128][136] rows of 272B
  #pragma unroll
  for (int n = 0; n < 4; ++n) {
    const int c = wc * 64 + n * 16 + lr;
    const float bv = bias[c];
    #pragma unroll
    for (int m = 0; m < 4; ++m) {
      const int row = wr * 64 + m * 16 + lg * 4;
      #pragma unroll
      for (int j = 0; j < 4; ++j) {
        float vv = acc[m][n][j] + bv;
        vv = vv > 0.f ? vv : (__expf(vv) - 1.f);
        hs[(row + j) * 136 + c] = f2bf(vv);
      }
    }
  }
  __syncthreads();
  const int r2 = tid >> 1, hf = tid & 1;
  const uint4* srow = reinterpret_cast<const uint4*>((const char*)hs + r2 * 272 + hf * 128);
  uint4* drow = reinterpret_cast<uint4*>(hbf + (size_t)(m0 + r2) * COUT_ + hf * 64);
  #pragma unroll
  for (int u = 0; u < 8; ++u) drow[u] = srow[u];
}

// ---------------- pool: CSR build (count / scan / fill), then row-major gather ----------

__global__ __launch_bounds__(256) void pool_count(const int* __restrict__ dr,
                                                  int* __restrict__ counts) {
  int e = blockIdx.x * 256 + threadIdx.x;
  if (e < NNZ_) atomicAdd(&counts[dr[e]], 1);
}

__global__ __launch_bounds__(256) void pool_scan(const int* __restrict__ counts,
                                                 int* __restrict__ offsets,
                                                 int* __restrict__ cursor) {
  __shared__ int part[256];
  const int t = threadIdx.x;
  const int c0 = t * 49;
  int s = 0;
  for (int i = 0; i < 49; ++i) {
    int j = c0 + i;
    if (j < VOUT_) s += counts[j];
  }
  part[t] = s;
  __syncthreads();
  #pragma unroll
  for (int off = 1; off < 256; off <<= 1) {
    int v = (t >= off) ? part[t - off] : 0;
    __syncthreads();
    part[t] += v;
    __syncthreads();
  }
  int run = part[t] - s;                 // exclusive prefix of my chunk
  for (int i = 0; i < 49; ++i) {
    int j = c0 + i;
    if (j < VOUT_) {
      offsets[j] = run; cursor[j] = run;
      run += counts[j];
    }
  }
  if (t == 255) offsets[VOUT_] = part[255];   // == NNZ_
}

__global__ __launch_bounds__(256) void pool_fill(const int* __restrict__ dr,
                                                 const int* __restrict__ dc,
                                                 const float* __restrict__ dd,
                                                 int* __restrict__ cursor,
                                                 int2* __restrict__ elist) {
  int e = blockIdx.x * 256 + threadIdx.x;
  if (e < NNZ_) {
    int slot = atomicAdd(&cursor[dr[e]], 1);
    elist[slot] = make_int2(dc[e], __float_as_int(dd[e]));
  }
}

__global__ __launch_bounds__(256) void pool_rows(const unsigned short* __restrict__ hbf,
                                                 const int* __restrict__ offsets,
                                                 const int2* __restrict__ elist,
                                                 float* __restrict__ out) {
  const int row = blockIdx.x;
  const int bg = threadIdx.x >> 5;     // batch 0..7
  const int lc = threadIdx.x & 31;     // c-quad 0..31
  const int s = offsets[row], e1 = offsets[row + 1];
  const unsigned short* hb = hbf + (size_t)bg * (V_ * COUT_) + lc * 4;
  float4 acc = {0.f, 0.f, 0.f, 0.f};
  for (int e = s; e < e1; ++e) {
    int2 en = elist[e];
    float d = __int_as_float(en.y);
    ushort4 v = *reinterpret_cast<const ushort4*>(hb + (size_t)en.x * COUT_);
    acc.x += d * bf2f(v.x);
    acc.y += d * bf2f(v.y);
    acc.z += d * bf2f(v.z);
    acc.w += d * bf2f(v.w);
  }
  *reinterpret_cast<float4*>(out + ((size_t)bg * VOUT_ + row) * COUT_ + lc * 4) = acc;
}

extern "C" void kernel_launch(void* const* d_in, const int* in_sizes, int n_in,
                              void* d_out, int out_size, void* d_ws, size_t ws_size,
                              hipStream_t stream) {
  const float* x    = (const float*)d_in[0];
  const float* w    = (const float*)d_in[1];
  const float* bias = (const float*)d_in[2];
  const int*   sp   = (const int*)d_in[3];
  const int*   dr   = (const int*)d_in[4];
  const int*   dc   = (const int*)d_in[5];
  const float* dd   = (const float*)d_in[6];
  float* out = (float*)d_out;

  char* ws = (char*)d_ws;
  unsigned short* wfr = (unsigned short*)ws;                       // 147,456 B (frag-major)
  unsigned short* xbf = (unsigned short*)(ws + 147456);            // 51,200,000 B
  unsigned short* hbf = (unsigned short*)(ws + 51347456);          // 102,400,000 B
  int*  counts  = (int*) (ws + 153747456);                         // 50,000 B
  int*  cursor  = (int*) (ws + 153797456);                         // 50,000 B
  int*  offsets = (int*) (ws + 153847456);                         // 50,004 B
  int2* elist   = (int2*)(ws + 153897464);                         // 300,000 B

  convert_w_frag<<<36, 256, 0, stream>>>(w, wfr);
  convert_x<<<2048, 256, 0, stream>>>(x, xbf);
  hipMemsetAsync(counts, 0, VOUT_ * sizeof(int), stream);
  pool_count<<<(NNZ_ + 255) / 256, 256, 0, stream>>>(dr, counts);
  pool_scan<<<1, 256, 0, stream>>>(counts, offsets, cursor);
  pool_fill<<<(NNZ_ + 255) / 256, 256, 0, stream>>>(dr, dc, dd, cursor, elist);
  spiral_gemm<<<M_ / 128, 256, 0, stream>>>(xbf, wfr, bias, sp, hbf);
  pool_rows<<<VOUT_, 256, 0, stream>>>(hbf, offsets, elist, out);
}

// Round 6
// 199.000 us; speedup vs baseline: 1.1001x; 1.0580x over previous
//
#include <hip/hip_runtime.h>

#define B_    8
#define V_    50000
#define KNB   9
#define CIN_  64
#define COUT_ 128
#define VOUT_ 12500
#define NNZ_  37500
#define KTOT  576      // KNB*CIN_
#define M_    400000   // B_*V_
#define NWG   3125     // M_/128

typedef short bf16x8 __attribute__((ext_vector_type(8)));
typedef float f32x4  __attribute__((ext_vector_type(4)));

#define AS1 __attribute__((address_space(1)))
#define AS3 __attribute__((address_space(3)))

__device__ __forceinline__ unsigned short f2bf(float f) {
  unsigned u = __float_as_uint(f);
  u += 0x7fffu + ((u >> 16) & 1u);          // RNE
  return (unsigned short)(u >> 16);
}
__device__ __forceinline__ float bf2f(unsigned short u) {
  return __uint_as_float((unsigned)u << 16);
}

__device__ __forceinline__ void gld_lds16(const void* g, void* l) {
  __builtin_amdgcn_global_load_lds((const AS1 unsigned*)g, (AS3 unsigned*)l, 16, 0, 0);
}

// Weight -> MFMA-fragment-major bf16: chunk i (16B) holds, for
// lane=i&63, n=(i>>6)&3, wc=(i>>8)&1, ks=(i>>9)&1, t=i>>10:
//   W[col = wc*64+n*16+(lane&15)][k = t*64+ks*32+(lane>>4)*8 .. +8]
__global__ __launch_bounds__(256) void convert_w_frag(const float* __restrict__ w,
                                                      unsigned short* __restrict__ wfr) {
  int i = blockIdx.x * 256 + threadIdx.x;        // 0..9215 (grid sized exactly)
  int lane = i & 63, n = (i >> 6) & 3, wc = (i >> 8) & 1, ks = (i >> 9) & 1, t = i >> 10;
  int col = wc * 64 + n * 16 + (lane & 15);
  int k0 = t * 64 + ks * 32 + (lane >> 4) * 8;
  const float* src = w + (size_t)col * KTOT + k0;
  float4 f0 = reinterpret_cast<const float4*>(src)[0];
  float4 f1 = reinterpret_cast<const float4*>(src)[1];
  uint4 o;
  o.x = (unsigned)f2bf(f0.x) | ((unsigned)f2bf(f0.y) << 16);
  o.y = (unsigned)f2bf(f0.z) | ((unsigned)f2bf(f0.w) << 16);
  o.z = (unsigned)f2bf(f1.x) | ((unsigned)f2bf(f1.y) << 16);
  o.w = (unsigned)f2bf(f1.z) | ((unsigned)f2bf(f1.w) << 16);
  reinterpret_cast<uint4*>(wfr)[i] = o;
}

__global__ __launch_bounds__(256) void convert_x(const float* __restrict__ x,
                                                 unsigned short* __restrict__ xbf) {
  const int nq = B_ * V_ * CIN_ / 4;        // 6.4M float4 quads
  for (int q = blockIdx.x * 256 + threadIdx.x; q < nq; q += 2048 * 256) {
    float4 f = reinterpret_cast<const float4*>(x)[q];
    ushort4 o;
    o.x = f2bf(f.x); o.y = f2bf(f.y); o.z = f2bf(f.z); o.w = f2bf(f.w);
    reinterpret_cast<ushort4*>(xbf)[q] = o;
  }
}

// h = elu(gather(x) @ W^T + bias). 128x128 tile, 4 waves (2x2 of 64x64), BK=64.
// Occupancy-first structure: A-only LDS double buffer (32KB) + 34.8KB block total,
// JIT B-frag register loads, rolling idx prefetch, one __syncthreads per K-step
// (compiler-safe; TLP from 4 blocks/CU hides gather latency).
// Bijective XCD swizzle confines each XCD's random gather to ~1 batch slice.
__global__ __launch_bounds__(256, 4) void spiral_gemm(
    const unsigned short* __restrict__ xbf, const unsigned short* __restrict__ wfr,
    const float* __restrict__ bias, const int* __restrict__ sp,
    unsigned short* __restrict__ hbf)
{
  __shared__ char smem[34816];     // A: 2 x 16KB; epilogue reuses as hs[128][136]

  // ---- bijective XCD swizzle (nwg=3125: q=390, r=5)
  {
  }
  const int q_ = NWG / 8, r_ = NWG % 8;
  const int xcd = blockIdx.x & 7, pos = blockIdx.x >> 3;
  const int nbid = (xcd < r_) ? xcd * (q_ + 1) + pos
                              : r_ * (q_ + 1) + (xcd - r_) * q_ + pos;

  const int tid  = threadIdx.x;
  const int m0   = nbid * 128;
  const int wave = tid >> 6;
  const int lane = tid & 63;

  // ---- staging geometry: 4 rounds x 32 rows, 8 lanes x 16B chunks per 128B row
  const int rrow  = tid >> 3;                       // 0..31
  const int chunkoff = (((tid & 7) ^ (rrow & 7)) << 4); // inverse-swizzled source chunk

  unsigned boff[4];
  const int* spb[4];
  #pragma unroll
  for (int r = 0; r < 4; ++r) {
    int row = r * 32 + rrow;
    int m = m0 + row;
    int b = m / V_;
    int v = m - b * V_;
    boff[r] = (unsigned)b * (V_ * CIN_ * 2);        // byte offset of batch slice
    spb[r]  = sp + v * KNB;
  }

  // ---- compute geometry
  const int wr = wave >> 1, wc = wave & 1;
  const int lr = lane & 15, lg = lane >> 4;
  const bf16x8* wbase = (const bf16x8*)wfr + wc * 256 + lane;   // +((t*2+ks)*512 + n*64)

  f32x4 acc[4][4];
  #pragma unroll
  for (int i = 0; i < 4; ++i)
    #pragma unroll
    for (int j = 0; j < 4; ++j)
      acc[i][j] = (f32x4){0.f, 0.f, 0.f, 0.f};

  auto stageA = [&](char* Ab, const int (&idx)[4]) {
    #pragma unroll
    for (int r = 0; r < 4; ++r) {
      unsigned off = boff[r] + (unsigned)idx[r] * 128u + (unsigned)chunkoff;
      gld_lds16((const char*)xbf + off, Ab + (r * 32 + wave * 8) * 128);
    }
  };

  // ---- prologue: stage t=0, preload idx for t=1
  int idx[4];
  #pragma unroll
  for (int r = 0; r < 4; ++r) idx[r] = spb[r][0];
  stageA(smem, idx);
  #pragma unroll
  for (int r = 0; r < 4; ++r) idx[r] = spb[r][1];
  __syncthreads();      // drains vmcnt(0): A(0) staged & visible

  // ---- main loop: one syncthreads per K-step; keep rolled so idx loads stay rolling
  #pragma unroll 1
  for (int t = 0; t < KNB; ++t) {
    if (t + 1 < KNB) stageA(smem + 16384 * ((t + 1) & 1), idx);
    if (t + 2 < KNB) {
      #pragma unroll
      for (int r = 0; r < 4; ++r) idx[r] = spb[r][t + 2];
    }
    const char* Ab = smem + 16384 * (t & 1);
    #pragma unroll
    for (int ks = 0; ks < 2; ++ks) {
      // B(t,ks) fragments JIT from L1/L2 (16 regs live)
      bf16x8 breg[4];
      #pragma unroll
      for (int n = 0; n < 4; ++n)
        breg[n] = wbase[(t * 2 + ks) * 512 + n * 64];
      const int kb = ks * 64 + lg * 16;
      bf16x8 af[4];
      #pragma unroll
      for (int m = 0; m < 4; ++m) {
        int row = wr * 64 + m * 16 + lr;
        af[m] = *reinterpret_cast<const bf16x8*>(Ab + row * 128 + (kb ^ ((row & 7) << 4)));
      }
      __builtin_amdgcn_s_setprio(1);
      #pragma unroll
      for (int m = 0; m < 4; ++m)
        #pragma unroll
        for (int n = 0; n < 4; ++n)
          acc[m][n] = __builtin_amdgcn_mfma_f32_16x16x32_bf16(af[m], breg[n], acc[m][n], 0, 0, 0);
      __builtin_amdgcn_s_setprio(0);
    }
    __syncthreads();   // A(t+1) staged & visible; buffer t&1 free for reuse
  }

  // ---- epilogue: bias + ELU -> bf16, re-layout via LDS for coalesced 16B stores
  unsigned short* hs = (unsigned short*)smem;   // [128][136] rows of 272B
  #pragma unroll
  for (int n = 0; n < 4; ++n) {
    const int c = wc * 64 + n * 16 + lr;
    const float bv = bias[c];
    #pragma unroll
    for (int m = 0; m < 4; ++m) {
      const int row = wr * 64 + m * 16 + lg * 4;
      #pragma unroll
      for (int j = 0; j < 4; ++j) {
        float vv = acc[m][n][j] + bv;
        vv = vv > 0.f ? vv : (__expf(vv) - 1.f);
        hs[(row + j) * 136 + c] = f2bf(vv);
      }
    }
  }
  __syncthreads();
  const int r2 = tid >> 1, hf = tid & 1;
  const uint4* srow = reinterpret_cast<const uint4*>((const char*)hs + r2 * 272 + hf * 128);
  uint4* drow = reinterpret_cast<uint4*>(hbf + (size_t)(m0 + r2) * COUT_ + hf * 64);
  #pragma unroll
  for (int u = 0; u < 8; ++u) drow[u] = srow[u];
}

// ---------------- pool: CSR build (count / scan / fill), then row-major gather ----------

__global__ __launch_bounds__(256) void pool_count(const int* __restrict__ dr,
                                                  int* __restrict__ counts) {
  int e = blockIdx.x * 256 + threadIdx.x;
  if (e < NNZ_) atomicAdd(&counts[dr[e]], 1);
}

__global__ __launch_bounds__(256) void pool_scan(const int* __restrict__ counts,
                                                 int* __restrict__ offsets,
                                                 int* __restrict__ cursor) {
  __shared__ int part[256];
  const int t = threadIdx.x;
  const int c0 = t * 49;
  int s = 0;
  for (int i = 0; i < 49; ++i) {
    int j = c0 + i;
    if (j < VOUT_) s += counts[j];
  }
  part[t] = s;
  __syncthreads();
  #pragma unroll
  for (int off = 1; off < 256; off <<= 1) {
    int v = (t >= off) ? part[t - off] : 0;
    __syncthreads();
    part[t] += v;
    __syncthreads();
  }
  int run = part[t] - s;                 // exclusive prefix of my chunk
  for (int i = 0; i < 49; ++i) {
    int j = c0 + i;
    if (j < VOUT_) {
      offsets[j] = run; cursor[j] = run;
      run += counts[j];
    }
  }
  if (t == 255) offsets[VOUT_] = part[255];   // == NNZ_
}

__global__ __launch_bounds__(256) void pool_fill(const int* __restrict__ dr,
                                                 const int* __restrict__ dc,
                                                 const float* __restrict__ dd,
                                                 int* __restrict__ cursor,
                                                 int2* __restrict__ elist) {
  int e = blockIdx.x * 256 + threadIdx.x;
  if (e < NNZ_) {
    int slot = atomicAdd(&cursor[dr[e]], 1);
    elist[slot] = make_int2(dc[e], __float_as_int(dd[e]));
  }
}

__global__ __launch_bounds__(256) void pool_rows(const unsigned short* __restrict__ hbf,
                                                 const int* __restrict__ offsets,
                                                 const int2* __restrict__ elist,
                                                 float* __restrict__ out) {
  const int row = blockIdx.x;
  const int bg = threadIdx.x >> 5;     // batch 0..7
  const int lc = threadIdx.x & 31;     // c-quad 0..31
  const int s = offsets[row], e1 = offsets[row + 1];
  const unsigned short* hb = hbf + (size_t)bg * (V_ * COUT_) + lc * 4;
  float4 acc = {0.f, 0.f, 0.f, 0.f};
  for (int e = s; e < e1; ++e) {
    int2 en = elist[e];
    float d = __int_as_float(en.y);
    ushort4 v = *reinterpret_cast<const ushort4*>(hb + (size_t)en.x * COUT_);
    acc.x += d * bf2f(v.x);
    acc.y += d * bf2f(v.y);
    acc.z += d * bf2f(v.z);
    acc.w += d * bf2f(v.w);
  }
  *reinterpret_cast<float4*>(out + ((size_t)bg * VOUT_ + row) * COUT_ + lc * 4) = acc;
}

extern "C" void kernel_launch(void* const* d_in, const int* in_sizes, int n_in,
                              void* d_out, int out_size, void* d_ws, size_t ws_size,
                              hipStream_t stream) {
  const float* x    = (const float*)d_in[0];
  const float* w    = (const float*)d_in[1];
  const float* bias = (const float*)d_in[2];
  const int*   sp   = (const int*)d_in[3];
  const int*   dr   = (const int*)d_in[4];
  const int*   dc   = (const int*)d_in[5];
  const float* dd   = (const float*)d_in[6];
  float* out = (float*)d_out;

  char* ws = (char*)d_ws;
  unsigned short* wfr = (unsigned short*)ws;                       // 147,456 B (frag-major)
  unsigned short* xbf = (unsigned short*)(ws + 147456);            // 51,200,000 B
  unsigned short* hbf = (unsigned short*)(ws + 51347456);          // 102,400,000 B
  int*  counts  = (int*) (ws + 153747456);                         // 50,000 B
  int*  cursor  = (int*) (ws + 153797456);                         // 50,000 B
  int*  offsets = (int*) (ws + 153847456);                         // 50,004 B
  int2* elist   = (int2*)(ws + 153897464);                         // 300,000 B

  convert_w_frag<<<36, 256, 0, stream>>>(w, wfr);
  convert_x<<<2048, 256, 0, stream>>>(x, xbf);
  hipMemsetAsync(counts, 0, VOUT_ * sizeof(int), stream);
  pool_count<<<(NNZ_ + 255) / 256, 256, 0, stream>>>(dr, counts);
  pool_scan<<<1, 256, 0, stream>>>(counts, offsets, cursor);
  pool_fill<<<(NNZ_ + 255) / 256, 256, 0, stream>>>(dr, dc, dd, cursor, elist);
  spiral_gemm<<<NWG, 256, 0, stream>>>(xbf, wfr, bias, sp, hbf);
  pool_rows<<<VOUT_, 256, 0, stream>>>(hbf, offsets, elist, out);
}